// Round 2
// baseline (1569.941 us; speedup 1.0000x reference)
//
#include <hip/hip_runtime.h>

// LSTM B=4096, T=60, F=128, H=256.
// Round-2 design: weights REGISTER/LDS-RESIDENT (loaded once, reused all 60 steps).
// Grid = 256 blocks = 128 row-groups x 2 column-halves; block = 512 thr (8 waves).
// Each block: 32 batch rows x 512 gate-cols (= 128 hidden units x 4 gates).
// Per wave: 1 hidden 16-block x 4 gates; B-frags: ks 0..10 in VGPRs (176), ks 11 in LDS.
// Partner halves exchange h per step via double-buffered global hbuf (transposed
// [j][b], bf16) with agent-scope 8B atomics + per-pair release/acquire flags.
// zbuf is fragment-major -> conflict-free ds_read_b128 A-fragment loads.

#define T_STEPS 60
#define F_DIM 128
#define H_DIM 256
#define K_DIM 384
#define B_DIM 4096
#define BC 32

typedef __attribute__((ext_vector_type(8))) short short8;
typedef __attribute__((ext_vector_type(4))) float floatx4;

__device__ __forceinline__ short f2bf(float f) {  // fp32 -> bf16, RNE
    union { float f; unsigned u; } a; a.f = f;
    unsigned r = a.u + 0x7fffu + ((a.u >> 16) & 1u);
    return (short)(r >> 16);
}
__device__ __forceinline__ float bf2f(short b) {
    union { unsigned u; float f; } a; a.u = ((unsigned)(unsigned short)b) << 16;
    return a.f;
}
__device__ __forceinline__ float sigmoidf_(float x) { return 1.0f / (1.0f + __expf(-x)); }
__device__ __forceinline__ float tanhf_(float x) {
    float ax = fabsf(x);
    float e = __expf(-2.0f * ax);
    float t = (1.0f - e) / (1.0f + e);
    return copysignf(t, x);
}

// Pack gate weights into bf16 MFMA B-fragments (gate-interleaved).
// frag = nt*12 + ks; nt in [0,64): g = nt&3, jblk = nt>>2.
// lane l, elem e -> W_g[k = ks*32 + (l>>4)*8 + e][jblk*16 + (l&15)].
__global__ void pack_w_kernel(const float* __restrict__ Wf, const float* __restrict__ Wu,
                              const float* __restrict__ Wc, const float* __restrict__ Wo,
                              short* __restrict__ wpack) {
    int gt = blockIdx.x * 256 + threadIdx.x;
    int frag = gt >> 6;
    int lane = gt & 63;
    int nt = frag / 12;
    int ks = frag - nt * 12;
    int g = nt & 3;
    int jblk = nt >> 2;
    int k0 = ks * 32 + ((lane >> 4) << 3);
    int col = jblk * 16 + (lane & 15);
    const float* W = (g == 0) ? Wf : (g == 1) ? Wu : (g == 2) ? Wc : Wo;
    short8 v;
#pragma unroll
    for (int e = 0; e < 8; ++e)
        v[e] = f2bf(W[(size_t)(k0 + e) * H_DIM + col]);
    *(short8*)(wpack + (size_t)frag * 512 + lane * 8) = v;
}

// Head is linear: out[b] = h[b]·v + s.
__global__ void head_prep_kernel(const float* __restrict__ Wd1, const float* __restrict__ bd1,
                                 const float* __restrict__ Wd2, const float* __restrict__ bd2,
                                 float* __restrict__ vhead, float* __restrict__ shead) {
    int j = threadIdx.x;
    float s = 0.f;
    for (int k = 0; k < H_DIM; ++k)
        s += Wd1[(size_t)j * H_DIM + k] * Wd2[k];
    vhead[j] = s;
    if (j == 0) {
        float t = 0.f;
        for (int k = 0; k < H_DIM; ++k) t += bd1[k] * Wd2[k];
        shead[0] = t + bd2[0];
    }
}

__global__ __launch_bounds__(512, 2) void lstm_kernel(
        const float* __restrict__ x,
        const float* __restrict__ bfv, const float* __restrict__ buv,
        const float* __restrict__ bcv, const float* __restrict__ bov,
        const short* __restrict__ wpack,
        const float* __restrict__ vhead, const float* __restrict__ shead,
        unsigned long long* __restrict__ hbuf,   // [2][256][4096] bf16 as ull chunks
        unsigned* __restrict__ flags,            // [128][2]
        float* __restrict__ out)
{
    __shared__ __align__(16) short zbuf[2][12][512];   // fragment-major [mt][ks][frag]
    __shared__ __align__(16) short wlds[8][4][512];    // ks=11 B-frags per wave/gate
    __shared__ float rowsum[32];

    const int tid  = threadIdx.x;
    const int wave = tid >> 6;          // 0..7
    const int lane = tid & 63;
    const int quad = lane >> 4;
    const int l15  = lane & 15;

    const int bx = blockIdx.x;
    const int c  = (bx >> 3) & 1;                    // column-half
    const int r  = (bx & 7) + ((bx >> 4) << 3);      // row-group 0..127 (pair = bx^8, same XCD)
    const int b0 = r * BC;
    const int myfl = r * 2 + c;
    const int pfl  = r * 2 + (1 - c);

    // ---- load resident weights: this wave's hidden 16-block = 8c + wave ----
    const short* wp = wpack + (size_t)((8 * c + wave) * 4) * 12 * 512 + lane * 8;
    short8 wreg[11][4];
#pragma unroll
    for (int g = 0; g < 4; ++g) {
#pragma unroll
        for (int ks = 0; ks < 11; ++ks)
            wreg[ks][g] = *(const short8*)(wp + (size_t)(g * 12 + ks) * 512);
        short8 v = *(const short8*)(wp + (size_t)(g * 12 + 11) * 512);
        *(short8*)(&wlds[wave][g][lane * 8]) = v;
    }

    // zero zbuf (h region must be 0 at t=0)
    for (int i = tid; i < 2 * 12 * 512 / 2; i += 512) ((int*)zbuf)[i] = 0;
    __syncthreads();

    const int jl = c * 128 + wave * 16 + l15;        // this lane's hidden col
    const float bfr = bfv[jl], bur = buv[jl], bcr = bcv[jl], bor = bov[jl];

    float creg[2][4] = {};

    const size_t HB = (size_t)H_DIM * B_DIM / 4;     // ull per buffer

    for (int t = 0; t < T_STEPS; ++t) {
        // ---- stage x_t (fragment-major) ----
#pragma unroll
        for (int i = 0; i < 2; ++i) {
            int idx = tid + 512 * i;
            int lr = idx >> 5, f = (idx & 31) << 2;
            float4 xv = *(const float4*)(x + ((size_t)(b0 + lr) * T_STEPS + t) * F_DIM + f);
            int ks = f >> 5, qk = (f >> 3) & 3, e = f & 7, mt = lr >> 4, m16 = lr & 15;
            ushort4 h4;
            h4.x = (unsigned short)f2bf(xv.x);
            h4.y = (unsigned short)f2bf(xv.y);
            h4.z = (unsigned short)f2bf(xv.z);
            h4.w = (unsigned short)f2bf(xv.w);
            *(ushort4*)(&zbuf[mt][ks][(qk * 16 + m16) * 8 + e]) = h4;
        }

        // ---- stage h_t from hbuf[t&1] (both halves) ----
        if (t > 0) {
            if (tid == 0) {
                for (long it = 0; it < 4000000L; ++it) {
                    if (__hip_atomic_load(&flags[pfl], __ATOMIC_ACQUIRE,
                                          __HIP_MEMORY_SCOPE_AGENT) >= (unsigned)t) break;
                    __builtin_amdgcn_s_sleep(2);
                }
            }
            __syncthreads();  // partner's h visible to whole block
            const unsigned long long* hb = hbuf + (size_t)(t & 1) * HB;
#pragma unroll
            for (int i = 0; i < 4; ++i) {
                int ch = tid + 512 * i;
                int j = ch >> 3, q4 = ch & 7;
                unsigned long long v = __hip_atomic_load(
                    &hb[((size_t)j * B_DIM + b0) / 4 + q4],
                    __ATOMIC_RELAXED, __HIP_MEMORY_SCOPE_AGENT);
                int kg = F_DIM + j, ks = kg >> 5, kl = kg & 31, qk = kl >> 3, e = kl & 7;
                int mt = q4 >> 2, mb = (q4 & 3) * 4;
                short* zp = &zbuf[mt][ks][e];
                zp[(qk * 16 + mb + 0) * 8] = (short)(v);
                zp[(qk * 16 + mb + 1) * 8] = (short)(v >> 16);
                zp[(qk * 16 + mb + 2) * 8] = (short)(v >> 32);
                zp[(qk * 16 + mb + 3) * 8] = (short)(v >> 48);
            }
        }
        __syncthreads();   // staging complete

        // ---- compute: preacts + gates + h-store, per m-tile ----
        unsigned long long* hbw = hbuf + (size_t)((t + 1) & 1) * HB;
#pragma unroll
        for (int mt = 0; mt < 2; ++mt) {
            floatx4 acc0 = {}, acc1 = {}, acc2 = {}, acc3 = {};
#pragma unroll
            for (int ks = 0; ks < 11; ++ks) {
                short8 a = *(const short8*)(&zbuf[mt][ks][lane * 8]);
                acc0 = __builtin_amdgcn_mfma_f32_16x16x32_bf16(a, wreg[ks][0], acc0, 0, 0, 0);
                acc1 = __builtin_amdgcn_mfma_f32_16x16x32_bf16(a, wreg[ks][1], acc1, 0, 0, 0);
                acc2 = __builtin_amdgcn_mfma_f32_16x16x32_bf16(a, wreg[ks][2], acc2, 0, 0, 0);
                acc3 = __builtin_amdgcn_mfma_f32_16x16x32_bf16(a, wreg[ks][3], acc3, 0, 0, 0);
            }
            {
                short8 a = *(const short8*)(&zbuf[mt][11][lane * 8]);
                short8 b0f = *(const short8*)(&wlds[wave][0][lane * 8]);
                short8 b1f = *(const short8*)(&wlds[wave][1][lane * 8]);
                short8 b2f = *(const short8*)(&wlds[wave][2][lane * 8]);
                short8 b3f = *(const short8*)(&wlds[wave][3][lane * 8]);
                acc0 = __builtin_amdgcn_mfma_f32_16x16x32_bf16(a, b0f, acc0, 0, 0, 0);
                acc1 = __builtin_amdgcn_mfma_f32_16x16x32_bf16(a, b1f, acc1, 0, 0, 0);
                acc2 = __builtin_amdgcn_mfma_f32_16x16x32_bf16(a, b2f, acc2, 0, 0, 0);
                acc3 = __builtin_amdgcn_mfma_f32_16x16x32_bf16(a, b3f, acc3, 0, 0, 0);
            }
            unsigned long long hv = 0;
#pragma unroll
            for (int rr = 0; rr < 4; ++rr) {
                float fg = sigmoidf_(acc0[rr] + bfr);
                float ug = sigmoidf_(acc1[rr] + bur);
                float gg = tanhf_(acc2[rr] + bcr);
                float og = sigmoidf_(acc3[rr] + bor);
                float cn = fg * creg[mt][rr] + ug * gg;
                creg[mt][rr] = cn;
                float hn = og * tanhf_(cn);
                hv |= ((unsigned long long)(unsigned short)f2bf(hn)) << (16 * rr);
            }
            // h rows mt*16+quad*4 .. +4, col jl  (transposed hbuf[j][b])
            __hip_atomic_store(&hbw[((size_t)jl * B_DIM + b0 + mt * 16 + quad * 4) / 4],
                               hv, __ATOMIC_RELAXED, __HIP_MEMORY_SCOPE_AGENT);
        }
        __syncthreads();   // zbuf reads done (WAR for next stage) + h-stores drained (vmcnt0)
        if (tid == 0) {
            __threadfence();
            __hip_atomic_store(&flags[myfl], (unsigned)(t + 1),
                               __ATOMIC_RELEASE, __HIP_MEMORY_SCOPE_AGENT);
        }
    }

    // ---- head: out[b] += sum_{own j half} h60[b][j]*v[j] (+ s once) ----
    if (tid < 32) rowsum[tid] = 0.f;
    __syncthreads();
    const unsigned long long* hb0 = hbuf;   // h_60 lives in buffer (59+1)&1 = 0
#pragma unroll
    for (int i = 0; i < 2; ++i) {
        int ch = tid + 512 * i;
        int j = c * 128 + (ch >> 3), q4 = ch & 7;
        unsigned long long v = __hip_atomic_load(&hb0[((size_t)j * B_DIM + b0) / 4 + q4],
                                                 __ATOMIC_RELAXED, __HIP_MEMORY_SCOPE_AGENT);
        float vh = vhead[j];
#pragma unroll
        for (int i2 = 0; i2 < 4; ++i2)
            atomicAdd(&rowsum[q4 * 4 + i2], bf2f((short)(v >> (16 * i2))) * vh);
    }
    __syncthreads();
    if (tid < 32)
        atomicAdd(&out[b0 + tid], rowsum[tid] + (c == 0 ? shead[0] : 0.f));
}

extern "C" void kernel_launch(void* const* d_in, const int* in_sizes, int n_in,
                              void* d_out, int out_size, void* d_ws, size_t ws_size,
                              hipStream_t stream) {
    (void)in_sizes; (void)n_in; (void)ws_size;
    const float* x   = (const float*)d_in[0];
    const float* Wf  = (const float*)d_in[1];
    const float* bfv = (const float*)d_in[2];
    const float* Wu  = (const float*)d_in[3];
    const float* buv = (const float*)d_in[4];
    const float* Wc  = (const float*)d_in[5];
    const float* bcv = (const float*)d_in[6];
    const float* Wo  = (const float*)d_in[7];
    const float* bov = (const float*)d_in[8];
    const float* Wd1 = (const float*)d_in[9];
    const float* bd1 = (const float*)d_in[10];
    const float* Wd2 = (const float*)d_in[11];
    const float* bd2 = (const float*)d_in[12];

    char* ws = (char*)d_ws;
    short* wpack = (short*)ws;                                   // 768 KB
    size_t off = (size_t)K_DIM * 1024 * 2;
    unsigned long long* hbuf = (unsigned long long*)(ws + off);  // 4 MB
    off += (size_t)2 * H_DIM * B_DIM * 2;
    float* vhead = (float*)(ws + off); off += H_DIM * 4;
    float* shead = (float*)(ws + off); off += 16;
    unsigned* flags = (unsigned*)(ws + off);                     // 1 KB

    hipMemsetAsync(flags, 0, 128 * 2 * sizeof(unsigned), stream);
    hipMemsetAsync(d_out, 0, (size_t)out_size * sizeof(float), stream);
    pack_w_kernel<<<192, 256, 0, stream>>>(Wf, Wu, Wc, Wo, wpack);
    head_prep_kernel<<<1, 256, 0, stream>>>(Wd1, bd1, Wd2, bd2, vhead, shead);
    lstm_kernel<<<256, 512, 0, stream>>>(x, bfv, buv, bcv, bov, wpack, vhead, shead,
                                         hbuf, flags, (float*)d_out);
}